// Round 1
// 1418.336 us; speedup vs baseline: 1.3027x; 1.3027x over previous
//
#include <hip/hip_runtime.h>
#include <math.h>

// Problem constants (fixed by setup_inputs)
#define TT 64
#define BB 16
#define SS 128
#define DD 512
#define NBLK 256
#define NTH 256
#define NSHARD 8
#define SHSTRIDE 64            // unsigned stride between shard counters (256 B)
#define BD (BB*DD)             // 8192
#define OUT_HR   (TT*BD)       // 524288
#define OUT_CR   (OUT_HR + BD)
#define OUT_HW   (OUT_CR + BD)
#define OUT_CW   (OUT_HW + BD)
#define OUT_MF   (OUT_CW + BD) // 557056
#define MAGIC 0x13579BDFu

// workspace float offsets (after 4096-byte header)
#define HRR_OFF 0              // hr ring [65][16][512]
#define HWR_OFF 532480         // hw ring [65][16][512]
#define MR_OFF  1064960        // m ring  [64][16][512]
#define SP_OFF  1589248        // sim partials [16][16][128]
#define GE_OFF  1622016        // gE [256 blk][64 t][16 b][8 c] = 2M floats

// LDS float offsets (dynamic, ~145 KB)
#define OFF_WHR  0             // Whh_r tile [16 kh][8 c][36]        4672
#define OFF_WHW  4672          // Whh_w tile                         4672
#define OFF_WFH  9344          // Wfused hr-half tile                4672
#define OFF_WFM  14016         // Wfused m-half tile                 4672
#define OFF_ABUF 18688         // hr staged, tiled [16 kh][16 b][36] 9472
#define OFF_ML   28160         // M slice [32][128]                  4096
#define OFF_PRED 32256         // shared scratch: 4224 floats
                               //   predAC = +0 [16][132]; predB = +2112 [16][132]
                               //   simP   = +0 [32][132];  mpart = +0 [256]
#define OFF_GFB  36480         // 128 (B-dot reduced, consumed in C)
#define OFF_GFT  36608         // 128 (A/C-dot reduced, same-phase)
#define OFF_ZL   36736         // 256: ping-pong z (iter parity: even -> +0, odd -> +128)
#define OFF_BFL  36992         // 8   (fused write bias)
#define OFF_SMW  37000         // 8   (softmax wave scratch; +6,+7 = hrdot partials)
#define LDS_FLOATS 37008
#define LDS_BYTES  (LDS_FLOATS*4)
#define KH_W 292               // weight tile kh-stride (8*36+4: bank-spread)
#define KH_A 592               // abuf kh-stride (16*36+16: bank-spread)

#define COLC(c) (((c) >> 1) * DD + dr0 + ((c) & 1))

__device__ __forceinline__ float sigf(float x) { return 1.f / (1.f + __expf(-x)); }

// agent-scope store/load for cross-block data
__device__ __forceinline__ void stg(float* p, float v) {
  __hip_atomic_store(p, v, __ATOMIC_RELAXED, __HIP_MEMORY_SCOPE_AGENT);
}
__device__ __forceinline__ float ldga(const float* p) {
  return __hip_atomic_load(p, __ATOMIC_RELAXED, __HIP_MEMORY_SCOPE_AGENT);
}

// 8-way sharded grid barrier: arrivals spread over 8 cachelines (32-way RMW
// contention instead of 256-way); waiters sum the monotonic shard counters.
__device__ __forceinline__ void barrive(unsigned* cnt, unsigned& ep, int shard) {
  __syncthreads();
  if (threadIdx.x == 0) {
    ++ep;
    asm volatile("s_waitcnt vmcnt(0)" ::: "memory");
    __hip_atomic_fetch_add(cnt + shard * SHSTRIDE, 1u, __ATOMIC_RELAXED,
                           __HIP_MEMORY_SCOPE_AGENT);
  }
}
__device__ __forceinline__ void bwait(unsigned* cnt, unsigned ep) {
  if (threadIdx.x == 0) {
    const unsigned target = ep * (unsigned)NBLK;
    for (;;) {
      unsigned s = 0;
#pragma unroll
      for (int k = 0; k < NSHARD; ++k)
        s += __hip_atomic_load(cnt + k * SHSTRIDE, __ATOMIC_RELAXED,
                               __HIP_MEMORY_SCOPE_AGENT);
      if (s >= target) break;
      __builtin_amdgcn_s_sleep(1);   // back off: don't hammer the lines being RMW'd
    }
  }
  __syncthreads();
}
__device__ __forceinline__ void lbar(unsigned* cnt, unsigned& ep, int shard) {
  barrive(cnt, ep, shard);
  bwait(cnt, ep);
}

__device__ __forceinline__ float dotf4(const float* __restrict__ a,
                                       const float* __restrict__ b, int n4) {
  const float4* a4 = (const float4*)a;
  const float4* b4 = (const float4*)b;
  float4 s = make_float4(0.f, 0.f, 0.f, 0.f);
#pragma unroll 8
  for (int k = 0; k < n4; ++k) {
    float4 x = a4[k], y = b4[k];
    s.x = fmaf(x.x, y.x, s.x); s.y = fmaf(x.y, y.y, s.y);
    s.z = fmaf(x.z, y.z, s.z); s.w = fmaf(x.w, y.w, s.w);
  }
  return (s.x + s.y) + (s.z + s.w);
}

// 8-col register-blocked dot over a 32-float k-chunk; a from LDS, w from tile
__device__ __forceinline__ void dot_pass8(const float* __restrict__ A,  // abuf + kh*KH_A + b*36
                                          const float* __restrict__ W,  // tile + kh*KH_W
                                          float* __restrict__ pout)     // PRED row + b*8
{
  float acc[8] = {0.f,0.f,0.f,0.f,0.f,0.f,0.f,0.f};
#pragma unroll
  for (int j = 0; j < 8; ++j) {
    float4 a4 = *(const float4*)(A + j*4);
#pragma unroll
    for (int c = 0; c < 8; ++c) {
      float4 w4 = *(const float4*)(W + c*36 + j*4);
      acc[c] = fmaf(a4.x, w4.x, acc[c]); acc[c] = fmaf(a4.y, w4.y, acc[c]);
      acc[c] = fmaf(a4.z, w4.z, acc[c]); acc[c] = fmaf(a4.w, w4.w, acc[c]);
    }
  }
  *(float4*)(pout)   = make_float4(acc[0],acc[1],acc[2],acc[3]);
  *(float4*)(pout+4) = make_float4(acc[4],acc[5],acc[6],acc[7]);
}

// 8-col dot over a 64-float chunk; a from GLOBAL row, w from tiles
__device__ __forceinline__ void dot_pass8g(const float* __restrict__ ag, // global row + khq*64
                                           const float* __restrict__ Wb, // tile base
                                           int khq,
                                           float* __restrict__ pout)
{
  float acc[8] = {0.f,0.f,0.f,0.f,0.f,0.f,0.f,0.f};
#pragma unroll
  for (int jj = 0; jj < 2; ++jj) {
    const float* Wt = Wb + (khq*2 + jj)*KH_W;
#pragma unroll
    for (int j = 0; j < 8; ++j) {
      float4 a4 = *(const float4*)(ag + jj*32 + j*4);
#pragma unroll
      for (int c = 0; c < 8; ++c) {
        float4 w4 = *(const float4*)(Wt + c*36 + j*4);
        acc[c] = fmaf(a4.x, w4.x, acc[c]); acc[c] = fmaf(a4.y, w4.y, acc[c]);
        acc[c] = fmaf(a4.z, w4.z, acc[c]); acc[c] = fmaf(a4.w, w4.w, acc[c]);
      }
    }
  }
  *(float4*)(pout)   = make_float4(acc[0],acc[1],acc[2],acc[3]);
  *(float4*)(pout+4) = make_float4(acc[4],acc[5],acc[6],acc[7]);
}

__global__ void __launch_bounds__(NTH) memnet(
    const float* __restrict__ emb, const float* __restrict__ M_in,
    const float* __restrict__ hr0, const float* __restrict__ cr0,
    const float* __restrict__ hw0, const float* __restrict__ cw0,
    const float* __restrict__ Wih_r, const float* __restrict__ Whh_r,
    const float* __restrict__ bih_r, const float* __restrict__ bhh_r,
    const float* __restrict__ Wih_w, const float* __restrict__ Whh_w,
    const float* __restrict__ bih_w, const float* __restrict__ bhh_w,
    const float* __restrict__ Wc, const float* __restrict__ bc,
    float* __restrict__ out,
    unsigned* flagp, unsigned* cntp, float* __restrict__ wsf)
{
  extern __shared__ float L[];
  const int tid = threadIdx.x;
  const int bid = blockIdx.x;
  const int shard = bid & (NSHARD - 1);

  // roles (every block has all three)
  const int mb  = bid & 15;          // M-slice batch
  const int mdh = bid >> 4;          // M-slice d-chunk: d in [mdh*32, +32)
  const int dr0 = 2 * bid;           // owned hidden dims {dr0, dr0+1}

  float* hrr = wsf + HRR_OFF;
  float* hwr = wsf + HWR_OFF;
  float* mr  = wsf + MR_OFF;
  float* sp  = wsf + SP_OFF;
  float* gE  = wsf + GE_OFF + bid * (TT * 128);

  // ---- init handshake ----
  if (bid == 0) {
    if (tid == 0) {
#pragma unroll
      for (int k = 0; k < NSHARD; ++k)
        __hip_atomic_store(cntp + k * SHSTRIDE, 0u, __ATOMIC_RELAXED,
                           __HIP_MEMORY_SCOPE_AGENT);
      asm volatile("s_waitcnt vmcnt(0)" ::: "memory");
      __hip_atomic_store(flagp, MAGIC, __ATOMIC_RELAXED, __HIP_MEMORY_SCOPE_AGENT);
    }
  } else if (tid == 0) {
    while (__hip_atomic_load(flagp, __ATOMIC_RELAXED, __HIP_MEMORY_SCOPE_AGENT) != MAGIC) {}
  }
  __syncthreads();
  unsigned ep = 0;

  // persistent cell states on threads [128,160): t -> (b=t&15, dl=t>>4)
  float cr = 0.f, cw = 0.f;
  if (tid >= 128 && tid < 160) {
    const int t = tid - 128, b = t & 15, dl = t >> 4;
    cr = cr0[b * DD + dr0 + dl];
    cw = cw0[b * DD + dr0 + dl];
  }

  // =========================== PROLOGUE ===========================
  // (1) Wih_w rows for own 8 write-cols -> ABUF region (temp flat [8][512])
  {
    float* wih = L + OFF_ABUF;
#pragma unroll
    for (int c = 0; c < 8; ++c)
      ((float2*)(wih + c * DD))[tid] = ((const float2*)(Wih_w + COLC(c) * DD))[tid];
  }
  __syncthreads();
  // (2) Wfused = Wih_w(own cols) @ Wc  -> WFH/WFM tiles; bfl
  {
    const float* wih = L + OFF_ABUF;
    float4 acc[8];
#pragma unroll
    for (int c = 0; c < 8; ++c) acc[c] = make_float4(0.f,0.f,0.f,0.f);
    const int k0 = tid * 4;
    for (int cc = 0; cc < DD; ++cc) {
      float4 wc4 = *(const float4*)(Wc + cc * 1024 + k0);
#pragma unroll
      for (int c = 0; c < 8; ++c) {
        const float wv = wih[c * DD + cc];
        acc[c].x = fmaf(wv, wc4.x, acc[c].x); acc[c].y = fmaf(wv, wc4.y, acc[c].y);
        acc[c].z = fmaf(wv, wc4.z, acc[c].z); acc[c].w = fmaf(wv, wc4.w, acc[c].w);
      }
    }
    const int kk = k0 & 511, kh = kk >> 5, jf = kk & 31;
    float* Tb = L + ((k0 < 512) ? OFF_WFH : OFF_WFM);
#pragma unroll
    for (int c = 0; c < 8; ++c)
      *(float4*)(Tb + kh*KH_W + c*36 + jf) = acc[c];
    if (tid < 8) {
      float s = 0.f;
      for (int cc = 0; cc < DD; ++cc) s = fmaf(wih[tid * DD + cc], bc[cc], s);
      L[OFF_BFL + tid] = s + bih_w[COLC(tid)] + bhh_w[COLC(tid)];
    }
  }
  __syncthreads();   // wih consumed; ABUF free
  // (3) Whh_r / Whh_w -> tiles
  {
    const int c = tid >> 5, r = tid & 31;
    const int kk = r * 16, kh = kk >> 5, jb = (r & 1) * 16;
#pragma unroll
    for (int set = 0; set < 2; ++set) {
      const float* Wsrc = set ? Whh_w : Whh_r;
      float* dst = L + (set ? OFF_WHW : OFF_WHR) + kh*KH_W + c*36 + jb;
      const float* src = Wsrc + COLC(c) * DD + kk;
#pragma unroll
      for (int u = 0; u < 4; ++u)
        *(float4*)(dst + u*4) = *(const float4*)(src + u*4);
    }
  }
  // (4) M slice transpose -> ML
  {
    const int d_l = tid >> 3, sq = tid & 7;
    const int d = mdh * 32 + d_l;
#pragma unroll 4
    for (int j = 0; j < 16; ++j) {
      const int s = sq * 16 + j;
      L[OFF_ML + d_l * 128 + s] = M_in[(mb * SS + s) * DD + d];
    }
  }
  // (5) gE precompute: gE[t][b][c] = emb[t][b]·Wih_r[col] + bih_r + bhh_r (all 64 t)
  {
    const int tH = tid >> 7, b = (tid >> 3) & 15, c = tid & 7;
    const int col = COLC(c);
    const float bias = bih_r[col] + bhh_r[col];
    const float* wrow = Wih_r + col * DD;
    for (int t = tH * 32; t < tH * 32 + 32; ++t) {
      gE[t * 128 + b * 8 + c] = dotf4(emb + (t * BB + b) * DD, wrow, DD / 4) + bias;
    }
  }
  // (6) stage hr0 -> ABUF (tiled)
  __syncthreads();
  {
#pragma unroll
    for (int j = 0; j < 8; ++j) {
      const int idx = j * 256 + tid;        // float4 index 0..2047
      const int b = idx >> 7, k4 = idx & 127;
      const int kh = k4 >> 3, jf = (k4 & 7) * 4;
      float4 v = ((const float4*)hr0)[idx];
      *(float4*)(L + OFF_ABUF + kh*KH_A + b*36 + jf) = v;
    }
  }
  __syncthreads();
  // (7) read-LSTM step 0 -> hr_1
  {
    const int kh = tid >> 4, b = tid & 15;
    dot_pass8(L + OFF_ABUF + kh*KH_A + b*36, L + OFF_WHR + kh*KH_W,
              L + OFF_PRED + kh*132 + b*8);
  }
  __syncthreads();
  if (tid < 128) {
    float s = 0.f;
#pragma unroll
    for (int k2 = 0; k2 < 16; ++k2) s += L[OFF_PRED + k2*132 + tid];
    L[OFF_GFT + tid] = s;
  }
  __syncthreads();
  if (tid >= 128 && tid < 160) {
    const int t = tid - 128, b = t & 15, dl = t >> 4;
    float g[4];
#pragma unroll
    for (int q = 0; q < 4; ++q) {
      const int bc = b * 8 + q * 2 + dl;
      g[q] = L[OFF_GFT + bc] + gE[0 * 128 + bc];
    }
    cr = sigf(g[1]) * cr + sigf(g[0]) * tanhf(g[2]);
    const float h2 = sigf(g[3]) * tanhf(cr);
    stg(hrr + 1 * BD + b * DD + dr0 + dl, h2);
  }
  lbar(cntp, ep, shard);
  // stage hr_1 -> ABUF for step 0
  {
    const float* src = hrr + 1 * BD;
#pragma unroll
    for (int j = 0; j < 8; ++j) {
      const int idx = j * 256 + tid;
      const int b = idx >> 7, k4 = idx & 127;
      const int kh = k4 >> 3, jf = (k4 & 7) * 4;
      float4 v = ((const float4*)src)[idx];
      *(float4*)(L + OFF_ABUF + kh*KH_A + b*36 + jf) = v;
    }
  }
  __syncthreads();

  // =========================== MAIN LOOP ===========================
  // 2 grid barriers per step (was 3): sim partials are computed against the
  // STALE M (one hw-update behind); the missing update is folded in after
  // bar1 via sim[s] = (1-z_prev[s]) * (stale_dot[s] + hr·hw_prev)  — the
  // hr·hw_prev term is a single scalar per batch. The physical M update is
  // fused into Phase B's m-dot.
  for (int i = 0; i < TT; ++i) {
    const int ii = i + 1;   // read-LSTM step computed this phase
    float* zold = L + OFF_ZL + ((i & 1) ^ 1) * 128;   // z_{i-1}
    float* znew = L + OFF_ZL + (i & 1) * 128;         // z_i (written this iter)

    // ---- Phase A exposed: sim partials vs current (stale) M ----
    {
      const int d_l = tid >> 3, sq = tid & 7;
      const float* Mrow = L + OFF_ML + d_l * 128;
      const float hrv = L[OFF_ABUF + mdh*KH_A + mb*36 + d_l];
#pragma unroll
      for (int j = 0; j < 4; ++j) {
        const int s4 = sq * 16 + j * 4;
        float4 M4 = *(const float4*)(Mrow + s4);
        float4 s;
        s.x = hrv * M4.x; s.y = hrv * M4.y; s.z = hrv * M4.z; s.w = hrv * M4.w;
        *(float4*)(L + OFF_PRED + d_l*132 + s4) = s;
      }
    }
    __syncthreads();
    if (tid < SS) {
      float v = 0.f;
#pragma unroll
      for (int dl2 = 0; dl2 < 32; ++dl2) v += L[OFF_PRED + dl2*132 + tid];
      stg(sp + (mb * 16 + mdh) * SS + tid, v);
    }
    barrive(cntp, ep, shard);

    // ---- Phase A hidden: read-LSTM hr-dot (Whh_r) + cell -> hr_{i+2} ----
    if (ii < TT) {
      {
        const int kh = tid >> 4, b = tid & 15;
        dot_pass8(L + OFF_ABUF + kh*KH_A + b*36, L + OFF_WHR + kh*KH_W,
                  L + OFF_PRED + kh*132 + b*8);
      }
      __syncthreads();
      if (tid < 128) {
        float s = 0.f;
#pragma unroll
        for (int k2 = 0; k2 < 16; ++k2) s += L[OFF_PRED + k2*132 + tid];
        L[OFF_GFT + tid] = s;
      }
      __syncthreads();
      if (tid >= 128 && tid < 160) {
        const int t = tid - 128, b = t & 15, dl = t >> 4;
        float g[4];
#pragma unroll
        for (int q = 0; q < 4; ++q) {
          const int bc = b * 8 + q * 2 + dl;
          g[q] = L[OFF_GFT + bc] + gE[ii * 128 + bc];
        }
        cr = sigf(g[1]) * cr + sigf(g[0]) * tanhf(g[2]);
        const float h2 = sigf(g[3]) * tanhf(cr);
        stg(hrr + (ii + 1) * BD + b * DD + dr0 + dl, h2);
        if (ii == TT - 1) {
          out[OUT_HR + b * DD + dr0 + dl] = h2;
          out[OUT_CR + b * DD + dr0 + dl] = cr;
        }
      }
    }
    bwait(cntp, ep);

    // ---- Phase B exposed: corrected sim -> softmax; fused M-update + m ----
    float vsum = 0.f;
    if (tid < SS) {
#pragma unroll
      for (int j = 0; j < 16; ++j) vsum += ldga(sp + (mb * 16 + j) * SS + tid);
    } else if (i > 0) {
      // waves 2,3: hrdot = hr_{i+1} · hw_{i-1}  (batch mb), wave-reduced
      const int t = tid - 128, k0 = t * 4;
      const float4 hw4 = *(const float4*)(hwr + i * BD + mb * DD + k0);
      const float4 a4  = *(const float4*)(L + OFF_ABUF + (k0 >> 5)*KH_A + mb*36 + (k0 & 31));
      float p = a4.x * hw4.x;
      p = fmaf(a4.y, hw4.y, p); p = fmaf(a4.z, hw4.z, p); p = fmaf(a4.w, hw4.w, p);
      for (int off = 32; off > 0; off >>= 1) p += __shfl_xor(p, off);
      if ((tid & 63) == 0) L[OFF_SMW + 6 + ((tid >> 6) & 1)] = p;
    }
    __syncthreads();
    if (tid < SS) {
      float v = vsum;
      if (i > 0) {
        const float hrdot = L[OFF_SMW + 6] + L[OFF_SMW + 7];
        v = (1.f - zold[tid]) * (v + hrdot);
      }
      float wm = v;
      for (int off = 32; off > 0; off >>= 1) wm = fmaxf(wm, __shfl_xor(wm, off));
      if ((tid & 63) == 0) L[OFF_SMW + (tid >> 6)] = wm;
      vsum = v;                       // stash corrected sim
    }
    __syncthreads();
    if (tid < SS) {
      const float gmax = fmaxf(L[OFF_SMW], L[OFF_SMW + 1]);
      const float e = __expf(vsum - gmax);
      float sm = e;
      for (int off = 32; off > 0; off >>= 1) sm += __shfl_xor(sm, off);
      if ((tid & 63) == 0) L[OFF_SMW + 2 + (tid >> 6)] = sm;
      vsum = e;                       // stash exp
    }
    __syncthreads();
    if (tid < SS) znew[tid] = vsum / (L[OFF_SMW + 2] + L[OFF_SMW + 3]);
    __syncthreads();
    // fused physical M-update (z_{i-1}, hw_{i-1}) + m-dot (z_i)
    {
      const int d_l = tid >> 3, sq = tid & 7;
      float* Mrow = L + OFF_ML + d_l * 128;
      float mv = 0.f;
      if (i > 0) {
        const float hwv = hwr[i * BD + mb * DD + mdh * 32 + d_l];
#pragma unroll
        for (int j = 0; j < 4; ++j) {
          const int s4 = sq * 16 + j * 4;
          float4 M4  = *(float4*)(Mrow + s4);
          float4 zo4 = *(const float4*)(zold + s4);
          float4 zn4 = *(const float4*)(znew + s4);
          M4.x = (1.f - zo4.x) * (M4.x + hwv);
          M4.y = (1.f - zo4.y) * (M4.y + hwv);
          M4.z = (1.f - zo4.z) * (M4.z + hwv);
          M4.w = (1.f - zo4.w) * (M4.w + hwv);
          *(float4*)(Mrow + s4) = M4;
          mv = fmaf(zn4.x, M4.x, mv); mv = fmaf(zn4.y, M4.y, mv);
          mv = fmaf(zn4.z, M4.z, mv); mv = fmaf(zn4.w, M4.w, mv);
        }
      } else {
#pragma unroll
        for (int j = 0; j < 4; ++j) {
          const int s4 = sq * 16 + j * 4;
          float4 M4  = *(const float4*)(Mrow + s4);
          float4 zn4 = *(const float4*)(znew + s4);
          mv = fmaf(zn4.x, M4.x, mv); mv = fmaf(zn4.y, M4.y, mv);
          mv = fmaf(zn4.z, M4.z, mv); mv = fmaf(zn4.w, M4.w, mv);
        }
      }
      L[OFF_PRED + d_l * 8 + sq] = mv;
    }
    __syncthreads();
    if (tid < 32) {
      float mv = 0.f;
#pragma unroll
      for (int j = 0; j < 8; ++j) mv += L[OFF_PRED + tid * 8 + j];
      stg(mr + i * BD + mb * DD + mdh * 32 + tid, mv);
    }
    barrive(cntp, ep, shard);

    // ---- Phase B hidden: g_hr partials (hr · WF hr-half) -> predB ----
    {
      const int kh = tid >> 4, b = tid & 15;
      dot_pass8(L + OFF_ABUF + kh*KH_A + b*36, L + OFF_WFH + kh*KH_W,
                L + OFF_PRED + 2112 + kh*132 + b*8);
    }
    bwait(cntp, ep);

    // ---- Phase C: reduce g_hr; m-dot + hw-dot; write cell; stage hr ----
    if (tid < 128) {
      float s = 0.f;
#pragma unroll
      for (int k2 = 0; k2 < 16; ++k2) s += L[OFF_PRED + 2112 + k2*132 + tid];
      L[OFF_GFB + tid] = s;
    }
    {
      const int src = tid >> 7, khq = (tid >> 4) & 7, b = tid & 15;
      const float* ag;
      const float* Wb;
      if (src == 0) { ag = mr + i * BD + b * DD + khq * 64; Wb = L + OFF_WFM; }
      else {
        const float* hwsrc = (i == 0) ? hw0 : (hwr + i * BD);
        ag = hwsrc + b * DD + khq * 64; Wb = L + OFF_WHW;
      }
      dot_pass8g(ag, Wb, khq, L + OFF_PRED + (src * 8 + khq) * 132 + b * 8);
    }
    __syncthreads();
    if (tid < 128) {
      float s = 0.f;
#pragma unroll
      for (int k2 = 0; k2 < 16; ++k2) s += L[OFF_PRED + k2*132 + tid];
      L[OFF_GFT + tid] = s;
    }
    __syncthreads();
    if (tid >= 128 && tid < 160) {
      const int t = tid - 128, b = t & 15, dl = t >> 4;
      float g[4];
#pragma unroll
      for (int q = 0; q < 4; ++q) {
        const int c = q * 2 + dl, bc = b * 8 + c;
        g[q] = L[OFF_GFB + bc] + L[OFF_GFT + bc] + L[OFF_BFL + c];
      }
      cw = sigf(g[1]) * cw + sigf(g[0]) * tanhf(g[2]);
      const float h2 = sigf(g[3]) * tanhf(cw);
      const int d = dr0 + dl;
      stg(hwr + (i + 1) * BD + b * DD + d, h2);
      out[i * BD + b * DD + d] = h2;
      if (i == TT - 1) {
        out[OUT_HW + b * DD + d] = h2;
        out[OUT_CW + b * DD + d] = cw;
      }
    }
    // stage hr_{i+2} -> ABUF for next step (hr stores were flushed at bar2)
    if (i < TT - 1) {
      const float* src = hrr + (i + 2) * BD;
#pragma unroll
      for (int j = 0; j < 8; ++j) {
        const int idx = j * 256 + tid;
        const int b = idx >> 7, k4 = idx & 127;
        const int kh = k4 >> 3, jf = (k4 & 7) * 4;
        float4 v = ((const float4*)src)[idx];
        *(float4*)(L + OFF_ABUF + kh*KH_A + b*36 + jf) = v;
      }
    }
    __syncthreads();   // ABUF staged + PRED free before next Phase A
  }

  // final sync: hw_63 stores must be visible for the M epilogue
  lbar(cntp, ep, shard);

  // =========================== EPILOGUE: final M output ===========================
  {
    const int d_l = tid >> 3, sq = tid & 7;
    const int d = mdh * 32 + d_l;
    const float hwv = hwr[TT * BD + mb * DD + d];
    const float* zfin = L + OFF_ZL + ((TT - 1) & 1) * 128;   // z_63
#pragma unroll 4
    for (int j = 0; j < 16; ++j) {
      const int s = sq * 16 + j;
      const float nv = (1.f - zfin[s]) * (L[OFF_ML + d_l * 128 + s] + hwv);
      out[OUT_MF + (mb * SS + s) * DD + d] = nv;
    }
  }
}

extern "C" void kernel_launch(void* const* d_in, const int* in_sizes, int n_in,
                              void* d_out, int out_size, void* d_ws, size_t ws_size,
                              hipStream_t stream) {
  (void)in_sizes; (void)n_in; (void)out_size; (void)ws_size;
  const float* emb   = (const float*)d_in[0];
  const float* M_in  = (const float*)d_in[1];
  const float* hr0   = (const float*)d_in[2];
  const float* cr0   = (const float*)d_in[3];
  const float* hw0   = (const float*)d_in[4];
  const float* cw0   = (const float*)d_in[5];
  const float* Wih_r = (const float*)d_in[6];
  const float* Whh_r = (const float*)d_in[7];
  const float* bih_r = (const float*)d_in[8];
  const float* bhh_r = (const float*)d_in[9];
  const float* Wih_w = (const float*)d_in[10];
  const float* Whh_w = (const float*)d_in[11];
  const float* bih_w = (const float*)d_in[12];
  const float* bhh_w = (const float*)d_in[13];
  const float* Wc    = (const float*)d_in[14];
  const float* bc    = (const float*)d_in[15];
  float* out = (float*)d_out;

  char* wsb = (char*)d_ws;
  unsigned* flagp = (unsigned*)wsb;          // byte 0
  unsigned* cntp  = (unsigned*)(wsb + 1024); // 8 shard counters, 256 B apart
  float* wsf = (float*)(wsb + 4096);         // ~14.9 MB data region

  static int attr_set = -1;
  (void)attr_set;
  hipFuncSetAttribute((const void*)memnet,
                      hipFuncAttributeMaxDynamicSharedMemorySize, LDS_BYTES);

  hipLaunchKernelGGL(memnet, dim3(NBLK), dim3(NTH), LDS_BYTES, stream,
                     emb, M_in, hr0, cr0, hw0, cw0,
                     Wih_r, Whh_r, bih_r, bhh_r,
                     Wih_w, Whh_w, bih_w, bhh_w, Wc, bc,
                     out, flagp, cntp, wsf);
}